// Round 3
// baseline (893.308 us; speedup 1.0000x reference)
//
#include <hip/hip_runtime.h>

#define NN 100000
#define NU 50000
#define NI 50000
#define NE 1600000

typedef unsigned short u16;
typedef unsigned int u32;

typedef __attribute__((ext_vector_type(8))) short s16x8;
typedef __attribute__((ext_vector_type(4))) float f32x4;
typedef __attribute__((ext_vector_type(4))) unsigned short us4;

__device__ __forceinline__ float bf2f(u16 u){
  union { u32 i; float f; } v; v.i = ((u32)u) << 16; return v.f;
}
__device__ __forceinline__ u16 f2bf(float f){
  union { float f; u32 i; } v; v.f = f;
  u32 u = v.i;
  return (u16)((u + 0x7FFFu + ((u >> 16) & 1u)) >> 16);
}
__device__ __forceinline__ float lrelu(float x){ return x > 0.f ? x : 0.01f * x; }
// flush NaN/Inf to 0 so a dtype misread can never poison the output
__device__ __forceinline__ float san(float v){
  union { float f; u32 i; } u; u.f = v;
  return ((u.i & 0x7F800000u) == 0x7F800000u) ? 0.f : v;
}

// ---------------------------------------------------------------------------
// Weight pre-transpose (fp32 in -> bf16 transposed out)
// panels: 0-1 trans_w[256,128]->Ttw[128,256]; 2-4 ws[i]->Tw[i][128,128];
// 5-7 des_w[i]->Td[i]; 8-13 out_w[i][256,128]->To[i][128,256]
// ---------------------------------------------------------------------------
__global__ __launch_bounds__(256) void transpose_weights(
    const float* __restrict__ trans_w, const float* __restrict__ wsw,
    const float* __restrict__ desw, const float* __restrict__ outw,
    u16* __restrict__ Ttw, u16* __restrict__ Tw, u16* __restrict__ Td, u16* __restrict__ To)
{
  __shared__ u16 L[128][136];
  int b = blockIdx.x, t = threadIdx.x;
  const float* src; u16* dst; int stride;
  if (b < 2)      { src = trans_w + b*16384;        dst = Ttw + b*128;          stride = 256; }
  else if (b < 5) { int i = b-2; src = wsw  + i*16384; dst = Tw + i*16384;      stride = 128; }
  else if (b < 8) { int i = b-5; src = desw + i*16384; dst = Td + i*16384;      stride = 128; }
  else            { int i = (b-8)>>1, h = (b-8)&1;
                    src = outw + i*32768 + h*16384;    dst = To + i*32768 + h*128; stride = 256; }
  #pragma unroll
  for (int p = 0; p < 8; p++){
    int fi = (p*256 + t)*8;
    int r = fi >> 7, c = fi & 127;
    f32x4 v0 = *(const f32x4*)(src + r*128 + c);
    f32x4 v1 = *(const f32x4*)(src + r*128 + c + 4);
    L[c+0][r] = f2bf(san(v0.x)); L[c+1][r] = f2bf(san(v0.y));
    L[c+2][r] = f2bf(san(v0.z)); L[c+3][r] = f2bf(san(v0.w));
    L[c+4][r] = f2bf(san(v1.x)); L[c+5][r] = f2bf(san(v1.y));
    L[c+6][r] = f2bf(san(v1.z)); L[c+7][r] = f2bf(san(v1.w));
  }
  __syncthreads();
  #pragma unroll
  for (int p = 0; p < 8; p++){
    int fi = (p*256 + t)*8;
    int n = fi >> 7, k = fi & 127;
    us4 o0, o1;
    o0.x = L[n][k+0]; o0.y = L[n][k+1]; o0.z = L[n][k+2]; o0.w = L[n][k+3];
    o1.x = L[n][k+4]; o1.y = L[n][k+5]; o1.z = L[n][k+6]; o1.w = L[n][k+7];
    *(us4*)(dst + (size_t)n*stride + k)     = o0;
    *(us4*)(dst + (size_t)n*stride + k + 4) = o1;
  }
}

// ---------------------------------------------------------------------------
// Users: X[0:50000] = L2-normalized user_feat_emb (fp32 in, bf16 out)
// ---------------------------------------------------------------------------
__global__ __launch_bounds__(256) void norm_users(const float* __restrict__ ufe, u16* __restrict__ X)
{
  int gid = blockIdx.x*256 + threadIdx.x;
  int row = gid >> 6, lane = gid & 63;
  float2 v = *(const float2*)(ufe + (size_t)row*128 + lane*2);
  float a = san(v.x), b = san(v.y);
  float ss = a*a + b*b;
  #pragma unroll
  for (int off = 32; off; off >>= 1) ss += __shfl_xor(ss, off, 64);
  float inv = 1.0f / fmaxf(sqrtf(ss), 1e-12f);
  u32 o = (u32)f2bf(a*inv) | ((u32)f2bf(b*inv) << 16);
  *(u32*)(X + (size_t)row*128 + lane*2) = o;
}

// ---------------------------------------------------------------------------
// Items: X[50000+r] = L2norm(feat @ trans_w + trans_b). fp32 feat -> bf16 MFMA
// ---------------------------------------------------------------------------
__global__ __launch_bounds__(256) void trans_items(
    const float* __restrict__ feat, const u16* __restrict__ Ttw,
    const float* __restrict__ tb, u16* __restrict__ X)
{
  __shared__ u16 Af[128][136];
  __shared__ u16 Wl[128][136];
  __shared__ float rowss[128][9];
  __shared__ float rnorm[128];

  int t = threadIdx.x;
  int r0 = blockIdx.x * 128;
  int w = t >> 6, lane = t & 63;
  int l15 = lane & 15, q = lane >> 4;
  int m0 = (w & 1) * 64, n0 = (w >> 1) * 64;

  f32x4 acc[4][4];
  #pragma unroll
  for (int mi = 0; mi < 4; mi++)
    #pragma unroll
    for (int ni = 0; ni < 4; ni++){ acc[mi][ni].x = 0.f; acc[mi][ni].y = 0.f; acc[mi][ni].z = 0.f; acc[mi][ni].w = 0.f; }

  for (int half = 0; half < 2; half++){
    __syncthreads();
    #pragma unroll
    for (int p = 0; p < 8; p++){
      int fi = (p*256 + t)*8;
      int r = fi >> 7, c = fi & 127;
      int row = r0 + r;
      us4 o0 = {0,0,0,0}, o1 = {0,0,0,0};
      if (row < NI){
        f32x4 v0 = *(const f32x4*)(feat + (size_t)row*256 + half*128 + c);
        f32x4 v1 = *(const f32x4*)(feat + (size_t)row*256 + half*128 + c + 4);
        o0.x = f2bf(san(v0.x)); o0.y = f2bf(san(v0.y)); o0.z = f2bf(san(v0.z)); o0.w = f2bf(san(v0.w));
        o1.x = f2bf(san(v1.x)); o1.y = f2bf(san(v1.y)); o1.z = f2bf(san(v1.z)); o1.w = f2bf(san(v1.w));
      }
      *(us4*)&Af[r][c]     = o0;
      *(us4*)&Af[r][c + 4] = o1;
      *(us4*)&Wl[r][c]     = *(const us4*)(Ttw + (size_t)r*256 + half*128 + c);
      *(us4*)&Wl[r][c + 4] = *(const us4*)(Ttw + (size_t)r*256 + half*128 + c + 4);
    }
    __syncthreads();
    #pragma unroll
    for (int kc = 0; kc < 128; kc += 32){
      s16x8 afr[4], bfr[4];
      #pragma unroll
      for (int mi = 0; mi < 4; mi++) afr[mi] = *(const s16x8*)&Wl[m0 + 16*mi + l15][kc + 8*q];
      #pragma unroll
      for (int ni = 0; ni < 4; ni++) bfr[ni] = *(const s16x8*)&Af[n0 + 16*ni + l15][kc + 8*q];
      #pragma unroll
      for (int mi = 0; mi < 4; mi++)
        #pragma unroll
        for (int ni = 0; ni < 4; ni++)
          acc[mi][ni] = __builtin_amdgcn_mfma_f32_16x16x32_bf16(afr[mi], bfr[ni], acc[mi][ni], 0, 0, 0);
    }
  }

  float bias[4][4];
  #pragma unroll
  for (int mi = 0; mi < 4; mi++){
    int c0 = m0 + 16*mi + 4*q;
    f32x4 bv = *(const f32x4*)(tb + c0);
    bias[mi][0] = san(bv.x); bias[mi][1] = san(bv.y); bias[mi][2] = san(bv.z); bias[mi][3] = san(bv.w);
  }
  #pragma unroll
  for (int ni = 0; ni < 4; ni++){
    float ss = 0.f;
    #pragma unroll
    for (int mi = 0; mi < 4; mi++){
      float v0 = acc[mi][ni].x + bias[mi][0];
      float v1 = acc[mi][ni].y + bias[mi][1];
      float v2 = acc[mi][ni].z + bias[mi][2];
      float v3 = acc[mi][ni].w + bias[mi][3];
      ss += v0*v0 + v1*v1 + v2*v2 + v3*v3;
    }
    rowss[n0 + 16*ni + l15][(w & 1)*4 + q] = ss;
  }
  __syncthreads();
  if (t < 128){
    float s = 0.f;
    #pragma unroll
    for (int j = 0; j < 8; j++) s += rowss[t][j];
    rnorm[t] = 1.0f / fmaxf(sqrtf(s), 1e-12f);
  }
  __syncthreads();
  #pragma unroll
  for (int mi = 0; mi < 4; mi++){
    int c0 = m0 + 16*mi + 4*q;
    #pragma unroll
    for (int ni = 0; ni < 4; ni++){
      int r = n0 + 16*ni + l15;
      int row = r0 + r;
      if (row < NI){
        float inv = rnorm[r];
        us4 o;
        o.x = f2bf((acc[mi][ni].x + bias[mi][0]) * inv);
        o.y = f2bf((acc[mi][ni].y + bias[mi][1]) * inv);
        o.z = f2bf((acc[mi][ni].z + bias[mi][2]) * inv);
        o.w = f2bf((acc[mi][ni].w + bias[mi][3]) * inv);
        *(us4*)(X + (size_t)(NU + row)*128 + c0) = o;
      }
    }
  }
}

// ---------------------------------------------------------------------------
// CSR build
// ---------------------------------------------------------------------------
__global__ void zero_int(int* __restrict__ p, int n){
  int i = blockIdx.x*256 + threadIdx.x;
  if (i < n) p[i] = 0;
}
__global__ void hist_k(const int* __restrict__ dst, int* __restrict__ counts){
  int e = blockIdx.x*256 + threadIdx.x;
  if (e < NE){
    int d = dst[e];
    d = min(max(d, 0), NN - 1);
    atomicAdd(&counts[d], 1);
  }
}
__global__ __launch_bounds__(1024) void scan_k(const int* __restrict__ counts, int* __restrict__ row_ptr){
  __shared__ int lds[1024];
  __shared__ int carry;
  int t = threadIdx.x;
  if (t == 0) carry = 0;
  __syncthreads();
  for (int base = 0; base < NN; base += 4096){
    int idx = base + t*4;
    int4 v = {0,0,0,0};
    if (idx < NN) v = *(const int4*)(counts + idx);
    int s = v.x + v.y + v.z + v.w;
    lds[t] = s;
    __syncthreads();
    for (int off = 1; off < 1024; off <<= 1){
      int add = (t >= off) ? lds[t - off] : 0;
      __syncthreads();
      lds[t] += add;
      __syncthreads();
    }
    int incl = lds[t];
    int total = lds[1023];
    int run = carry;
    if (idx < NN){
      int e0 = run + incl - s;
      int4 o;
      o.x = e0; o.y = e0 + v.x; o.z = o.y + v.y; o.w = o.z + v.z;
      *(int4*)(row_ptr + idx) = o;
    }
    __syncthreads();
    if (t == 0) carry = run + total;
    __syncthreads();
  }
  if (t == 0) row_ptr[NN] = carry;
}
__global__ void fill_k(const int* __restrict__ src, const int* __restrict__ dst,
                       const int* __restrict__ row_ptr, int* __restrict__ cursor, int* __restrict__ esrc){
  int e = blockIdx.x*256 + threadIdx.x;
  if (e < NE){
    int d = dst[e];
    d = min(max(d, 0), NN - 1);
    int pos = atomicAdd(&cursor[d], 1);
    int idx = row_ptr[d] + pos;
    idx = min(max(idx, 0), NE - 1);
    esrc[idx] = src[e];
  }
}

// ---------------------------------------------------------------------------
// Aggregation: one wave per node; fp32 accumulate, bf16 store.
// ---------------------------------------------------------------------------
__global__ __launch_bounds__(256) void aggregate(
    const u16* __restrict__ X, const int* __restrict__ row_ptr,
    const int* __restrict__ esrc, u16* __restrict__ AGG)
{
  int gid = blockIdx.x*256 + threadIdx.x;
  int v = gid >> 6, lane = gid & 63;
  int jb = row_ptr[v], je = row_ptr[v + 1];
  jb = min(max(jb, 0), NE);
  je = min(max(je, jb), NE);
  float a0 = 0.f, a1 = 0.f;
  int j = jb;
  for (; j + 1 < je; j += 2){
    int s0 = esrc[j], s1 = esrc[j + 1];
    s0 = min(max(s0, 0), NN - 1);
    s1 = min(max(s1, 0), NN - 1);
    u32 p0 = *(const u32*)(X + (size_t)s0*128 + lane*2);
    u32 p1 = *(const u32*)(X + (size_t)s1*128 + lane*2);
    a0 += bf2f((u16)(p0 & 0xFFFF)) + bf2f((u16)(p1 & 0xFFFF));
    a1 += bf2f((u16)(p0 >> 16))    + bf2f((u16)(p1 >> 16));
  }
  if (j < je){
    int s0 = esrc[j];
    s0 = min(max(s0, 0), NN - 1);
    u32 p0 = *(const u32*)(X + (size_t)s0*128 + lane*2);
    a0 += bf2f((u16)(p0 & 0xFFFF));
    a1 += bf2f((u16)(p0 >> 16));
  }
  u32 o = (u32)f2bf(a0) | ((u32)f2bf(a1) << 16);
  *(u32*)(AGG + (size_t)v*128 + lane*2) = o;
}

// ---------------------------------------------------------------------------
// Fused dense layer. Last layer writes fp32 to d_out, others bf16 to X.
// ---------------------------------------------------------------------------
__global__ __launch_bounds__(256) void layer_fused(
    const u16* __restrict__ AGG, const float* __restrict__ nembF,
    const u16* __restrict__ Twi, const u16* __restrict__ Tdi,
    const float* __restrict__ dbF, const u16* __restrict__ Toi,
    const float* __restrict__ obF, u16* __restrict__ XoutB,
    float* __restrict__ XoutF, int last)
{
  __shared__ u16 Ab[128][136];   // agg (stage1 B), then u (stage3b B)
  __shared__ u16 Hb[128][136];   // h   (stage2/3a B)
  __shared__ u16 Wl[128][136];   // current weight (A operand)

  int t = threadIdx.x;
  int r0 = blockIdx.x * 128;
  int w = t >> 6, lane = t & 63;
  int l15 = lane & 15, q = lane >> 4;
  int m0 = (w & 1) * 64, n0 = (w >> 1) * 64;

  f32x4 acc[4][4];

#define ZERO_ACC() \
  { _Pragma("unroll") for (int mi = 0; mi < 4; mi++) \
      { _Pragma("unroll") for (int ni = 0; ni < 4; ni++) \
        { acc[mi][ni].x = 0.f; acc[mi][ni].y = 0.f; acc[mi][ni].z = 0.f; acc[mi][ni].w = 0.f; } } }

#define STAGE_W(SRC, STRIDE, KOFF) \
  { _Pragma("unroll") for (int p = 0; p < 8; p++){ \
      int fi = (p*256 + t)*8; int r = fi >> 7, c = fi & 127; \
      *(us4*)&Wl[r][c]     = *(const us4*)((SRC) + (size_t)r*(STRIDE) + (KOFF) + c); \
      *(us4*)&Wl[r][c + 4] = *(const us4*)((SRC) + (size_t)r*(STRIDE) + (KOFF) + c + 4); } }

#define GEMM128(BARR) \
  { _Pragma("unroll") for (int kc = 0; kc < 128; kc += 32){ \
      s16x8 afr[4], bfr[4]; \
      _Pragma("unroll") for (int mi = 0; mi < 4; mi++) afr[mi] = *(const s16x8*)&Wl[m0 + 16*mi + l15][kc + 8*q]; \
      _Pragma("unroll") for (int ni = 0; ni < 4; ni++) bfr[ni] = *(const s16x8*)&BARR[n0 + 16*ni + l15][kc + 8*q]; \
      _Pragma("unroll") for (int mi = 0; mi < 4; mi++) \
        { _Pragma("unroll") for (int ni = 0; ni < 4; ni++) \
          acc[mi][ni] = __builtin_amdgcn_mfma_f32_16x16x32_bf16(afr[mi], bfr[ni], acc[mi][ni], 0, 0, 0); } } }

  #pragma unroll
  for (int p = 0; p < 8; p++){
    int fi = (p*256 + t)*8;
    int r = fi >> 7, c = fi & 127;
    int row = r0 + r;
    us4 o0 = {0,0,0,0}, o1 = {0,0,0,0};
    if (row < NN){
      o0 = *(const us4*)(AGG + (size_t)row*128 + c);
      o1 = *(const us4*)(AGG + (size_t)row*128 + c + 4);
    }
    *(us4*)&Ab[r][c]     = o0;
    *(us4*)&Ab[r][c + 4] = o1;
    *(us4*)&Wl[r][c]     = *(const us4*)(Twi + (size_t)r*128 + c);
    *(us4*)&Wl[r][c + 4] = *(const us4*)(Twi + (size_t)r*128 + c + 4);
  }
  __syncthreads();

  // stage 1: H^T = Tw * Agg^T
  ZERO_ACC();
  GEMM128(Ab);
  __syncthreads();

  #pragma unroll
  for (int mi = 0; mi < 4; mi++){
    #pragma unroll
    for (int ni = 0; ni < 4; ni++){
      us4 o;
      o.x = f2bf(lrelu(acc[mi][ni].x));
      o.y = f2bf(lrelu(acc[mi][ni].y));
      o.z = f2bf(lrelu(acc[mi][ni].z));
      o.w = f2bf(lrelu(acc[mi][ni].w));
      *(us4*)&Hb[n0 + 16*ni + l15][m0 + 16*mi + 4*q] = o;
    }
  }
  STAGE_W(Tdi, 128, 0);
  __syncthreads();

  // stage 2: U^T = Td * H^T
  ZERO_ACC();
  GEMM128(Hb);
  __syncthreads();

  #pragma unroll
  for (int mi = 0; mi < 4; mi++){
    int c0 = m0 + 16*mi + 4*q;
    f32x4 dbv = *(const f32x4*)(dbF + c0);
    float db0 = san(dbv.x), db1 = san(dbv.y), db2 = san(dbv.z), db3 = san(dbv.w);
    #pragma unroll
    for (int ni = 0; ni < 4; ni++){
      int r = n0 + 16*ni + l15;
      int row = r0 + r;
      float e0 = 0.f, e1 = 0.f, e2 = 0.f, e3 = 0.f;
      if (row < NN){
        f32x4 nev = *(const f32x4*)(nembF + (size_t)row*128 + c0);
        e0 = san(nev.x); e1 = san(nev.y); e2 = san(nev.z); e3 = san(nev.w);
      }
      us4 o;
      o.x = f2bf(lrelu(acc[mi][ni].x + db0 + e0));
      o.y = f2bf(lrelu(acc[mi][ni].y + db1 + e1));
      o.z = f2bf(lrelu(acc[mi][ni].z + db2 + e2));
      o.w = f2bf(lrelu(acc[mi][ni].w + db3 + e3));
      *(us4*)&Ab[r][c0] = o;
    }
  }
  STAGE_W(Toi, 256, 0);
  __syncthreads();

  // stage 3a: X^T += To[:,0:128] * H^T
  ZERO_ACC();
  GEMM128(Hb);
  __syncthreads();
  STAGE_W(Toi, 256, 128);
  __syncthreads();
  // stage 3b: X^T += To[:,128:256] * U^T
  GEMM128(Ab);

  #pragma unroll
  for (int mi = 0; mi < 4; mi++){
    int c0 = m0 + 16*mi + 4*q;
    f32x4 obv = *(const f32x4*)(obF + c0);
    float b0 = san(obv.x), b1 = san(obv.y), b2 = san(obv.z), b3 = san(obv.w);
    #pragma unroll
    for (int ni = 0; ni < 4; ni++){
      int r = n0 + 16*ni + l15;
      int row = r0 + r;
      if (row < NN){
        if (last){
          f32x4 o;
          o.x = lrelu(acc[mi][ni].x + b0);
          o.y = lrelu(acc[mi][ni].y + b1);
          o.z = lrelu(acc[mi][ni].z + b2);
          o.w = lrelu(acc[mi][ni].w + b3);
          *(f32x4*)(XoutF + (size_t)row*128 + c0) = o;
        } else {
          us4 o;
          o.x = f2bf(lrelu(acc[mi][ni].x + b0));
          o.y = f2bf(lrelu(acc[mi][ni].y + b1));
          o.z = f2bf(lrelu(acc[mi][ni].z + b2));
          o.w = f2bf(lrelu(acc[mi][ni].w + b3));
          *(us4*)(XoutB + (size_t)row*128 + c0) = o;
        }
      }
    }
  }
#undef ZERO_ACC
#undef STAGE_W
#undef GEMM128
}

// ---------------------------------------------------------------------------
__global__ void copy_ufe(const float4* __restrict__ s, float4* __restrict__ d, int n){
  int i = blockIdx.x*256 + threadIdx.x;
  if (i < n){
    float4 v = s[i];
    v.x = san(v.x); v.y = san(v.y); v.z = san(v.z); v.w = san(v.w);
    d[i] = v;
  }
}

// ---------------------------------------------------------------------------
extern "C" void kernel_launch(void* const* d_in, const int* in_sizes, int n_in,
                              void* d_out, int out_size, void* d_ws, size_t ws_size,
                              hipStream_t stream)
{
  const float* feat = (const float*)d_in[0];
  const float* nemb = (const float*)d_in[1];
  const int*   src  = (const int*)d_in[2];
  const int*   dst  = (const int*)d_in[3];
  const float* ufe  = (const float*)d_in[4];
  const float* tw   = (const float*)d_in[5];
  const float* tb   = (const float*)d_in[6];
  const float* wsw  = (const float*)d_in[7];
  const float* desw = (const float*)d_in[8];
  const float* desb = (const float*)d_in[9];
  const float* outw = (const float*)d_in[10];
  const float* outb = (const float*)d_in[11];

  float* out  = (float*)d_out;
  float* outU = out + (size_t)NN*128;

  // bf16 X table aliases the first 25.6 MB of d_out's 51.2 MB fp32 region.
  // Layers 0/1 read/write it; layer 2 (after its aggregate consumed X)
  // overwrites the full region with the fp32 result.
  u16* X = (u16*)out;

  char* p = (char*)d_ws;                               // total ~33.4 MB
  u16*   AGG = (u16*)p;    p += (size_t)NN*128*2;      // bf16 aggregation
  u16*   Ttw = (u16*)p;    p += (size_t)2*16384*2;
  u16*   Tw  = (u16*)p;    p += (size_t)3*16384*2;
  u16*   Td  = (u16*)p;    p += (size_t)3*16384*2;
  u16*   To  = (u16*)p;    p += (size_t)3*32768*2;
  int* row_ptr = (int*)p;  p += (size_t)100004*4;
  int* counts  = (int*)p;  p += (size_t)100000*4;
  int* esrc    = (int*)p;  p += (size_t)NE*4;

  transpose_weights<<<14, 256, 0, stream>>>(tw, wsw, desw, outw, Ttw, Tw, Td, To);
  norm_users<<<NU/4, 256, 0, stream>>>(ufe, X);
  trans_items<<<(NI + 127)/128, 256, 0, stream>>>(feat, Ttw, tb, X);

  zero_int<<<(NN + 255)/256, 256, 0, stream>>>(counts, NN);
  hist_k<<<(NE + 255)/256, 256, 0, stream>>>(dst, counts);
  scan_k<<<1, 1024, 0, stream>>>(counts, row_ptr);
  zero_int<<<(NN + 255)/256, 256, 0, stream>>>(counts, NN);
  fill_k<<<(NE + 255)/256, 256, 0, stream>>>(src, dst, row_ptr, counts, esrc);

  for (int i = 0; i < 3; i++){
    aggregate<<<NN/4, 256, 0, stream>>>(X, row_ptr, esrc, AGG);
    layer_fused<<<(NN + 127)/128, 256, 0, stream>>>(AGG, nemb,
        Tw + (size_t)i*16384, Td + (size_t)i*16384, desb + (size_t)i*128,
        To + (size_t)i*32768, outb + (size_t)i*128, X, out, (i == 2) ? 1 : 0);
  }
  copy_ufe<<<(NU*128/4 + 255)/256, 256, 0, stream>>>((const float4*)ufe, (float4*)outU, NU*128/4);
}

// Round 4
// 787.790 us; speedup vs baseline: 1.1339x; 1.1339x over previous
//
#include <hip/hip_runtime.h>

#define NN 100000
#define NU 50000
#define NI 50000
#define NE 1600000
#define NSLICE 5
#define SLICEW 20000

typedef unsigned short u16;
typedef unsigned int u32;

typedef __attribute__((ext_vector_type(8))) short s16x8;
typedef __attribute__((ext_vector_type(4))) float f32x4;
typedef __attribute__((ext_vector_type(4))) unsigned short us4;

__device__ __forceinline__ float bf2f(u16 u){
  union { u32 i; float f; } v; v.i = ((u32)u) << 16; return v.f;
}
__device__ __forceinline__ u16 f2bf(float f){
  union { float f; u32 i; } v; v.f = f;
  u32 u = v.i;
  return (u16)((u + 0x7FFFu + ((u >> 16) & 1u)) >> 16);
}
__device__ __forceinline__ u32 pack2(float lo, float hi){
  return (u32)f2bf(lo) | ((u32)f2bf(hi) << 16);
}
__device__ __forceinline__ float lrelu(float x){ return x > 0.f ? x : 0.01f * x; }
__device__ __forceinline__ float san(float v){
  union { float f; u32 i; } u; u.f = v;
  return ((u.i & 0x7F800000u) == 0x7F800000u) ? 0.f : v;
}

// ---------------------------------------------------------------------------
// Weight pre-transpose (fp32 in -> bf16 transposed out)
// ---------------------------------------------------------------------------
__global__ __launch_bounds__(256) void transpose_weights(
    const float* __restrict__ trans_w, const float* __restrict__ wsw,
    const float* __restrict__ desw, const float* __restrict__ outw,
    u16* __restrict__ Ttw, u16* __restrict__ Tw, u16* __restrict__ Td, u16* __restrict__ To)
{
  __shared__ u16 L[128][136];
  int b = blockIdx.x, t = threadIdx.x;
  const float* src; u16* dst; int stride;
  if (b < 2)      { src = trans_w + b*16384;        dst = Ttw + b*128;          stride = 256; }
  else if (b < 5) { int i = b-2; src = wsw  + i*16384; dst = Tw + i*16384;      stride = 128; }
  else if (b < 8) { int i = b-5; src = desw + i*16384; dst = Td + i*16384;      stride = 128; }
  else            { int i = (b-8)>>1, h = (b-8)&1;
                    src = outw + i*32768 + h*16384;    dst = To + i*32768 + h*128; stride = 256; }
  #pragma unroll
  for (int p = 0; p < 8; p++){
    int fi = (p*256 + t)*8;
    int r = fi >> 7, c = fi & 127;
    f32x4 v0 = *(const f32x4*)(src + r*128 + c);
    f32x4 v1 = *(const f32x4*)(src + r*128 + c + 4);
    L[c+0][r] = f2bf(san(v0.x)); L[c+1][r] = f2bf(san(v0.y));
    L[c+2][r] = f2bf(san(v0.z)); L[c+3][r] = f2bf(san(v0.w));
    L[c+4][r] = f2bf(san(v1.x)); L[c+5][r] = f2bf(san(v1.y));
    L[c+6][r] = f2bf(san(v1.z)); L[c+7][r] = f2bf(san(v1.w));
  }
  __syncthreads();
  #pragma unroll
  for (int p = 0; p < 8; p++){
    int fi = (p*256 + t)*8;
    int n = fi >> 7, k = fi & 127;
    us4 o0, o1;
    o0.x = L[n][k+0]; o0.y = L[n][k+1]; o0.z = L[n][k+2]; o0.w = L[n][k+3];
    o1.x = L[n][k+4]; o1.y = L[n][k+5]; o1.z = L[n][k+6]; o1.w = L[n][k+7];
    *(us4*)(dst + (size_t)n*stride + k)     = o0;
    *(us4*)(dst + (size_t)n*stride + k + 4) = o1;
  }
}

// ---------------------------------------------------------------------------
__global__ __launch_bounds__(256) void norm_users(const float* __restrict__ ufe, u16* __restrict__ X)
{
  int gid = blockIdx.x*256 + threadIdx.x;
  int row = gid >> 6, lane = gid & 63;
  float2 v = *(const float2*)(ufe + (size_t)row*128 + lane*2);
  float a = san(v.x), b = san(v.y);
  float ss = a*a + b*b;
  #pragma unroll
  for (int off = 32; off; off >>= 1) ss += __shfl_xor(ss, off, 64);
  float inv = 1.0f / fmaxf(sqrtf(ss), 1e-12f);
  *(u32*)(X + (size_t)row*128 + lane*2) = pack2(a*inv, b*inv);
}

// ---------------------------------------------------------------------------
// Items: X[50000+r] = L2norm(feat @ trans_w + trans_b)
// ---------------------------------------------------------------------------
__global__ __launch_bounds__(256) void trans_items(
    const float* __restrict__ feat, const u16* __restrict__ Ttw,
    const float* __restrict__ tb, u16* __restrict__ X)
{
  __shared__ u16 Af[128][136];
  __shared__ u16 Wl[128][136];
  __shared__ float rowss[128][9];
  __shared__ float rnorm[128];

  int t = threadIdx.x;
  int r0 = blockIdx.x * 128;
  int w = t >> 6, lane = t & 63;
  int l15 = lane & 15, q = lane >> 4;
  int m0 = (w & 1) * 64, n0 = (w >> 1) * 64;

  f32x4 acc[4][4];
  #pragma unroll
  for (int mi = 0; mi < 4; mi++)
    #pragma unroll
    for (int ni = 0; ni < 4; ni++){ acc[mi][ni].x = 0.f; acc[mi][ni].y = 0.f; acc[mi][ni].z = 0.f; acc[mi][ni].w = 0.f; }

  for (int half = 0; half < 2; half++){
    __syncthreads();
    #pragma unroll
    for (int p = 0; p < 8; p++){
      int fi = (p*256 + t)*8;
      int r = fi >> 7, c = fi & 127;
      int row = r0 + r;
      us4 o0 = {0,0,0,0}, o1 = {0,0,0,0};
      if (row < NI){
        f32x4 v0 = *(const f32x4*)(feat + (size_t)row*256 + half*128 + c);
        f32x4 v1 = *(const f32x4*)(feat + (size_t)row*256 + half*128 + c + 4);
        o0.x = f2bf(san(v0.x)); o0.y = f2bf(san(v0.y)); o0.z = f2bf(san(v0.z)); o0.w = f2bf(san(v0.w));
        o1.x = f2bf(san(v1.x)); o1.y = f2bf(san(v1.y)); o1.z = f2bf(san(v1.z)); o1.w = f2bf(san(v1.w));
      }
      *(us4*)&Af[r][c]     = o0;
      *(us4*)&Af[r][c + 4] = o1;
      *(us4*)&Wl[r][c]     = *(const us4*)(Ttw + (size_t)r*256 + half*128 + c);
      *(us4*)&Wl[r][c + 4] = *(const us4*)(Ttw + (size_t)r*256 + half*128 + c + 4);
    }
    __syncthreads();
    #pragma unroll
    for (int kc = 0; kc < 128; kc += 32){
      s16x8 afr[4], bfr[4];
      #pragma unroll
      for (int mi = 0; mi < 4; mi++) afr[mi] = *(const s16x8*)&Wl[m0 + 16*mi + l15][kc + 8*q];
      #pragma unroll
      for (int ni = 0; ni < 4; ni++) bfr[ni] = *(const s16x8*)&Af[n0 + 16*ni + l15][kc + 8*q];
      #pragma unroll
      for (int mi = 0; mi < 4; mi++)
        #pragma unroll
        for (int ni = 0; ni < 4; ni++)
          acc[mi][ni] = __builtin_amdgcn_mfma_f32_16x16x32_bf16(afr[mi], bfr[ni], acc[mi][ni], 0, 0, 0);
    }
  }

  float bias[4][4];
  #pragma unroll
  for (int mi = 0; mi < 4; mi++){
    int c0 = m0 + 16*mi + 4*q;
    f32x4 bv = *(const f32x4*)(tb + c0);
    bias[mi][0] = san(bv.x); bias[mi][1] = san(bv.y); bias[mi][2] = san(bv.z); bias[mi][3] = san(bv.w);
  }
  #pragma unroll
  for (int ni = 0; ni < 4; ni++){
    float ss = 0.f;
    #pragma unroll
    for (int mi = 0; mi < 4; mi++){
      float v0 = acc[mi][ni].x + bias[mi][0];
      float v1 = acc[mi][ni].y + bias[mi][1];
      float v2 = acc[mi][ni].z + bias[mi][2];
      float v3 = acc[mi][ni].w + bias[mi][3];
      ss += v0*v0 + v1*v1 + v2*v2 + v3*v3;
    }
    rowss[n0 + 16*ni + l15][(w & 1)*4 + q] = ss;
  }
  __syncthreads();
  if (t < 128){
    float s = 0.f;
    #pragma unroll
    for (int j = 0; j < 8; j++) s += rowss[t][j];
    rnorm[t] = 1.0f / fmaxf(sqrtf(s), 1e-12f);
  }
  __syncthreads();
  #pragma unroll
  for (int mi = 0; mi < 4; mi++){
    int c0 = m0 + 16*mi + 4*q;
    #pragma unroll
    for (int ni = 0; ni < 4; ni++){
      int r = n0 + 16*ni + l15;
      int row = r0 + r;
      if (row < NI){
        float inv = rnorm[r];
        us4 o;
        o.x = f2bf((acc[mi][ni].x + bias[mi][0]) * inv);
        o.y = f2bf((acc[mi][ni].y + bias[mi][1]) * inv);
        o.z = f2bf((acc[mi][ni].z + bias[mi][2]) * inv);
        o.w = f2bf((acc[mi][ni].w + bias[mi][3]) * inv);
        *(us4*)(X + (size_t)(NU + row)*128 + c0) = o;
      }
    }
  }
}

// ---------------------------------------------------------------------------
// CSR build
// ---------------------------------------------------------------------------
__global__ void zero_int(int* __restrict__ p, int n){
  int i = blockIdx.x*256 + threadIdx.x;
  if (i < n) p[i] = 0;
}
__global__ void hist_k(const int* __restrict__ dst, int* __restrict__ counts){
  int e = blockIdx.x*256 + threadIdx.x;
  if (e < NE){
    int d = dst[e];
    d = min(max(d, 0), NN - 1);
    atomicAdd(&counts[d], 1);
  }
}
__global__ __launch_bounds__(1024) void scan_k(const int* __restrict__ counts, int* __restrict__ row_ptr){
  __shared__ int lds[1024];
  __shared__ int carry;
  int t = threadIdx.x;
  if (t == 0) carry = 0;
  __syncthreads();
  for (int base = 0; base < NN; base += 4096){
    int idx = base + t*4;
    int4 v = {0,0,0,0};
    if (idx < NN) v = *(const int4*)(counts + idx);
    int s = v.x + v.y + v.z + v.w;
    lds[t] = s;
    __syncthreads();
    for (int off = 1; off < 1024; off <<= 1){
      int add = (t >= off) ? lds[t - off] : 0;
      __syncthreads();
      lds[t] += add;
      __syncthreads();
    }
    int incl = lds[t];
    int total = lds[1023];
    int run = carry;
    if (idx < NN){
      int e0 = run + incl - s;
      int4 o;
      o.x = e0; o.y = e0 + v.x; o.z = o.y + v.y; o.w = o.z + v.z;
      *(int4*)(row_ptr + idx) = o;
    }
    __syncthreads();
    if (t == 0) carry = run + total;
    __syncthreads();
  }
}

// Sliced fill: pass p handles dst in [d0,d1); esrc window for that range is
// ~1.3 MB -> stays L2-resident so the random 4B scatter doesn't write-allocate
// a 64B HBM line per edge. row_ptr doubles as cursor (post-fill it holds the
// shifted prefix: row_ptr[v] == original row_ptr[v+1]).
__global__ __launch_bounds__(256) void fill_slice(
    const int* __restrict__ src, const int* __restrict__ dst,
    int* __restrict__ row_ptr, int* __restrict__ esrc, int d0, int d1)
{
  int e = blockIdx.x*256 + threadIdx.x;
  if (e < NE){
    int d = dst[e];
    if (d >= d0 && d < d1){
      d = min(max(d, 0), NN - 1);
      int pos = atomicAdd(&row_ptr[d], 1);
      pos = min(max(pos, 0), NE - 1);
      esrc[pos] = src[e];
    }
  }
}

// ---------------------------------------------------------------------------
// Aggregation: one wave per node; quarter-wave (16 lanes x 16B) per edge,
// up to 8 edges in flight per wave; shuffle-reduce across sub-groups.
// row_ptr is the post-fill shifted prefix: jb = row_ptr[v-1], je = row_ptr[v].
// ---------------------------------------------------------------------------
__global__ __launch_bounds__(256) void aggregate(
    const u16* __restrict__ X, const int* __restrict__ row_ptr,
    const int* __restrict__ esrc, u16* __restrict__ AGG)
{
  int gid = blockIdx.x*256 + threadIdx.x;
  int v = gid >> 6, lane = gid & 63;
  int sub = lane >> 4, li = lane & 15;
  int jb = (v == 0) ? 0 : row_ptr[v - 1];
  int je = row_ptr[v];
  jb = min(max(jb, 0), NE);
  je = min(max(je, jb), NE);

  float a0=0.f,a1=0.f,a2=0.f,a3=0.f,a4=0.f,a5=0.f,a6=0.f,a7=0.f;

  int j = jb + sub;
  for (; j + 4 < je; j += 8){
    int s0 = esrc[j];     s0 = min(max(s0, 0), NN - 1);
    int s1 = esrc[j + 4]; s1 = min(max(s1, 0), NN - 1);
    uint4 p0 = *(const uint4*)(X + (size_t)s0*128 + li*8);
    uint4 p1 = *(const uint4*)(X + (size_t)s1*128 + li*8);
    a0 += bf2f((u16)(p0.x & 0xFFFF)); a1 += bf2f((u16)(p0.x >> 16));
    a2 += bf2f((u16)(p0.y & 0xFFFF)); a3 += bf2f((u16)(p0.y >> 16));
    a4 += bf2f((u16)(p0.z & 0xFFFF)); a5 += bf2f((u16)(p0.z >> 16));
    a6 += bf2f((u16)(p0.w & 0xFFFF)); a7 += bf2f((u16)(p0.w >> 16));
    a0 += bf2f((u16)(p1.x & 0xFFFF)); a1 += bf2f((u16)(p1.x >> 16));
    a2 += bf2f((u16)(p1.y & 0xFFFF)); a3 += bf2f((u16)(p1.y >> 16));
    a4 += bf2f((u16)(p1.z & 0xFFFF)); a5 += bf2f((u16)(p1.z >> 16));
    a6 += bf2f((u16)(p1.w & 0xFFFF)); a7 += bf2f((u16)(p1.w >> 16));
  }
  for (; j < je; j += 4){
    int s0 = esrc[j]; s0 = min(max(s0, 0), NN - 1);
    uint4 p0 = *(const uint4*)(X + (size_t)s0*128 + li*8);
    a0 += bf2f((u16)(p0.x & 0xFFFF)); a1 += bf2f((u16)(p0.x >> 16));
    a2 += bf2f((u16)(p0.y & 0xFFFF)); a3 += bf2f((u16)(p0.y >> 16));
    a4 += bf2f((u16)(p0.z & 0xFFFF)); a5 += bf2f((u16)(p0.z >> 16));
    a6 += bf2f((u16)(p0.w & 0xFFFF)); a7 += bf2f((u16)(p0.w >> 16));
  }

  a0 += __shfl_xor(a0, 16, 64); a0 += __shfl_xor(a0, 32, 64);
  a1 += __shfl_xor(a1, 16, 64); a1 += __shfl_xor(a1, 32, 64);
  a2 += __shfl_xor(a2, 16, 64); a2 += __shfl_xor(a2, 32, 64);
  a3 += __shfl_xor(a3, 16, 64); a3 += __shfl_xor(a3, 32, 64);
  a4 += __shfl_xor(a4, 16, 64); a4 += __shfl_xor(a4, 32, 64);
  a5 += __shfl_xor(a5, 16, 64); a5 += __shfl_xor(a5, 32, 64);
  a6 += __shfl_xor(a6, 16, 64); a6 += __shfl_xor(a6, 32, 64);
  a7 += __shfl_xor(a7, 16, 64); a7 += __shfl_xor(a7, 32, 64);

  if (sub == 0){
    uint4 o;
    o.x = pack2(a0, a1); o.y = pack2(a2, a3);
    o.z = pack2(a4, a5); o.w = pack2(a6, a7);
    *(uint4*)(AGG + (size_t)v*128 + li*8) = o;
  }
}

// ---------------------------------------------------------------------------
// Fused dense layer. Weight A-fragments come straight from global (L2-hot);
// LDS only holds the two activation tiles -> 69.6 KB -> 2 blocks/CU.
// ---------------------------------------------------------------------------
__global__ __launch_bounds__(256, 2) void layer_fused(
    const u16* __restrict__ AGG, const float* __restrict__ nembF,
    const u16* __restrict__ Twi, const u16* __restrict__ Tdi,
    const float* __restrict__ dbF, const u16* __restrict__ Toi,
    const float* __restrict__ obF, u16* __restrict__ XoutB,
    float* __restrict__ XoutF, int last)
{
  __shared__ u16 Ab[128][136];   // agg (stage1 B), then u (stage3b B)
  __shared__ u16 Hb[128][136];   // h   (stage2/3a B)

  int t = threadIdx.x;
  int r0 = blockIdx.x * 128;
  int w = t >> 6, lane = t & 63;
  int l15 = lane & 15, q = lane >> 4;
  int m0 = (w & 1) * 64, n0 = (w >> 1) * 64;

  f32x4 acc[4][4];

#define ZERO_ACC() \
  { _Pragma("unroll") for (int mi = 0; mi < 4; mi++) \
      { _Pragma("unroll") for (int ni = 0; ni < 4; ni++) \
        { acc[mi][ni].x = 0.f; acc[mi][ni].y = 0.f; acc[mi][ni].z = 0.f; acc[mi][ni].w = 0.f; } } }

#define GEMMG(BARR, WBASE, WSTRIDE, WKOFF) \
  { s16x8 afr[4][4]; \
    _Pragma("unroll") for (int mi = 0; mi < 4; mi++) \
      { _Pragma("unroll") for (int kk = 0; kk < 4; kk++) \
          afr[mi][kk] = *(const s16x8*)((WBASE) + (size_t)(m0 + 16*mi + l15)*(WSTRIDE) + (WKOFF) + kk*32 + 8*q); } \
    _Pragma("unroll") for (int kk = 0; kk < 4; kk++){ \
      s16x8 bfr[4]; \
      _Pragma("unroll") for (int ni = 0; ni < 4; ni++) bfr[ni] = *(const s16x8*)&BARR[n0 + 16*ni + l15][kk*32 + 8*q]; \
      _Pragma("unroll") for (int mi = 0; mi < 4; mi++) \
        { _Pragma("unroll") for (int ni = 0; ni < 4; ni++) \
          acc[mi][ni] = __builtin_amdgcn_mfma_f32_16x16x32_bf16(afr[mi][kk], bfr[ni], acc[mi][ni], 0, 0, 0); } } }

  // stage agg tile into Ab
  #pragma unroll
  for (int p = 0; p < 8; p++){
    int fi = (p*256 + t)*8;
    int r = fi >> 7, c = fi & 127;
    int row = r0 + r;
    us4 o0 = {0,0,0,0}, o1 = {0,0,0,0};
    if (row < NN){
      o0 = *(const us4*)(AGG + (size_t)row*128 + c);
      o1 = *(const us4*)(AGG + (size_t)row*128 + c + 4);
    }
    *(us4*)&Ab[r][c]     = o0;
    *(us4*)&Ab[r][c + 4] = o1;
  }
  __syncthreads();

  // stage 1: H^T = Tw * Agg^T
  ZERO_ACC();
  GEMMG(Ab, Twi, 128, 0);

  // write h (lrelu) into Hb
  #pragma unroll
  for (int mi = 0; mi < 4; mi++){
    #pragma unroll
    for (int ni = 0; ni < 4; ni++){
      us4 o;
      o.x = f2bf(lrelu(acc[mi][ni].x));
      o.y = f2bf(lrelu(acc[mi][ni].y));
      o.z = f2bf(lrelu(acc[mi][ni].z));
      o.w = f2bf(lrelu(acc[mi][ni].w));
      *(us4*)&Hb[n0 + 16*ni + l15][m0 + 16*mi + 4*q] = o;
    }
  }
  __syncthreads();   // Hb complete; also guarantees all stage-1 reads of Ab done

  // stage 2: U^T = Td * H^T
  ZERO_ACC();
  GEMMG(Hb, Tdi, 128, 0);

  // write u = lrelu(. + des_b + node_emb) into Ab
  #pragma unroll
  for (int mi = 0; mi < 4; mi++){
    int c0 = m0 + 16*mi + 4*q;
    f32x4 dbv = *(const f32x4*)(dbF + c0);
    float db0 = san(dbv.x), db1 = san(dbv.y), db2 = san(dbv.z), db3 = san(dbv.w);
    #pragma unroll
    for (int ni = 0; ni < 4; ni++){
      int r = n0 + 16*ni + l15;
      int row = r0 + r;
      float e0 = 0.f, e1 = 0.f, e2 = 0.f, e3 = 0.f;
      if (row < NN){
        f32x4 nev = *(const f32x4*)(nembF + (size_t)row*128 + c0);
        e0 = san(nev.x); e1 = san(nev.y); e2 = san(nev.z); e3 = san(nev.w);
      }
      us4 o;
      o.x = f2bf(lrelu(acc[mi][ni].x + db0 + e0));
      o.y = f2bf(lrelu(acc[mi][ni].y + db1 + e1));
      o.z = f2bf(lrelu(acc[mi][ni].z + db2 + e2));
      o.w = f2bf(lrelu(acc[mi][ni].w + db3 + e3));
      *(us4*)&Ab[r][c0] = o;
    }
  }
  __syncthreads();   // u complete

  // stage 3: X^T = To[:,0:128]*H^T + To[:,128:256]*U^T
  ZERO_ACC();
  GEMMG(Hb, Toi, 256, 0);
  GEMMG(Ab, Toi, 256, 128);

  #pragma unroll
  for (int mi = 0; mi < 4; mi++){
    int c0 = m0 + 16*mi + 4*q;
    f32x4 obv = *(const f32x4*)(obF + c0);
    float b0 = san(obv.x), b1 = san(obv.y), b2 = san(obv.z), b3 = san(obv.w);
    #pragma unroll
    for (int ni = 0; ni < 4; ni++){
      int r = n0 + 16*ni + l15;
      int row = r0 + r;
      if (row < NN){
        if (last){
          f32x4 o;
          o.x = lrelu(acc[mi][ni].x + b0);
          o.y = lrelu(acc[mi][ni].y + b1);
          o.z = lrelu(acc[mi][ni].z + b2);
          o.w = lrelu(acc[mi][ni].w + b3);
          *(f32x4*)(XoutF + (size_t)row*128 + c0) = o;
        } else {
          us4 o;
          o.x = f2bf(lrelu(acc[mi][ni].x + b0));
          o.y = f2bf(lrelu(acc[mi][ni].y + b1));
          o.z = f2bf(lrelu(acc[mi][ni].z + b2));
          o.w = f2bf(lrelu(acc[mi][ni].w + b3));
          *(us4*)(XoutB + (size_t)row*128 + c0) = o;
        }
      }
    }
  }
#undef ZERO_ACC
#undef GEMMG
}

// ---------------------------------------------------------------------------
__global__ void copy_ufe(const float4* __restrict__ s, float4* __restrict__ d, int n){
  int i = blockIdx.x*256 + threadIdx.x;
  if (i < n){
    float4 v = s[i];
    v.x = san(v.x); v.y = san(v.y); v.z = san(v.z); v.w = san(v.w);
    d[i] = v;
  }
}

// ---------------------------------------------------------------------------
extern "C" void kernel_launch(void* const* d_in, const int* in_sizes, int n_in,
                              void* d_out, int out_size, void* d_ws, size_t ws_size,
                              hipStream_t stream)
{
  const float* feat = (const float*)d_in[0];
  const float* nemb = (const float*)d_in[1];
  const int*   src  = (const int*)d_in[2];
  const int*   dst  = (const int*)d_in[3];
  const float* ufe  = (const float*)d_in[4];
  const float* tw   = (const float*)d_in[5];
  const float* tb   = (const float*)d_in[6];
  const float* wsw  = (const float*)d_in[7];
  const float* desw = (const float*)d_in[8];
  const float* desb = (const float*)d_in[9];
  const float* outw = (const float*)d_in[10];
  const float* outb = (const float*)d_in[11];

  float* out  = (float*)d_out;
  float* outU = out + (size_t)NN*128;

  // bf16 X table aliases the first 25.6 MB of d_out; layer 2 overwrites the
  // full region with the fp32 result after its aggregate consumed X.
  u16* X = (u16*)out;

  char* p = (char*)d_ws;
  u16*   AGG = (u16*)p;    p += (size_t)NN*128*2;
  u16*   Ttw = (u16*)p;    p += (size_t)2*16384*2;
  u16*   Tw  = (u16*)p;    p += (size_t)3*16384*2;
  u16*   Td  = (u16*)p;    p += (size_t)3*16384*2;
  u16*   To  = (u16*)p;    p += (size_t)3*32768*2;
  int* row_ptr = (int*)p;  p += (size_t)100004*4;
  int* counts  = (int*)p;  p += (size_t)100000*4;
  int* esrc    = (int*)p;  p += (size_t)NE*4;

  transpose_weights<<<14, 256, 0, stream>>>(tw, wsw, desw, outw, Ttw, Tw, Td, To);
  norm_users<<<NU/4, 256, 0, stream>>>(ufe, X);
  trans_items<<<(NI + 127)/128, 256, 0, stream>>>(feat, Ttw, tb, X);

  zero_int<<<(NN + 255)/256, 256, 0, stream>>>(counts, NN);
  hist_k<<<(NE + 255)/256, 256, 0, stream>>>(dst, counts);
  scan_k<<<1, 1024, 0, stream>>>(counts, row_ptr);
  for (int s = 0; s < NSLICE; s++){
    fill_slice<<<(NE + 255)/256, 256, 0, stream>>>(src, dst, row_ptr, esrc,
        s*SLICEW, (s == NSLICE-1) ? NN : (s+1)*SLICEW);
  }

  for (int i = 0; i < 3; i++){
    aggregate<<<NN/4, 256, 0, stream>>>(X, row_ptr, esrc, AGG);
    layer_fused<<<(NN + 127)/128, 256, 0, stream>>>(AGG, nemb,
        Tw + (size_t)i*16384, Td + (size_t)i*16384, desb + (size_t)i*128,
        To + (size_t)i*32768, outb + (size_t)i*128, X, out, (i == 2) ? 1 : 0);
  }
  copy_ufe<<<(NU*128/4 + 255)/256, 256, 0, stream>>>((const float4*)ufe, (float4*)outU, NU*128/4);
}